// Round 3
// baseline (317.139 us; speedup 1.0000x reference)
//
#include <hip/hip_runtime.h>
#include <cstdint>

#define NROWS 16384
#define FDIM 64
#define HDIM 128
#define ODIM 512
#define KDIM 8192   // FDIM * HDIM

#define BM 256
#define BN 256
#define BK 64

typedef short bf16x8 __attribute__((ext_vector_type(8)));
typedef float f32x4 __attribute__((ext_vector_type(4)));
typedef uint32_t u32x4 __attribute__((ext_vector_type(4)));

__device__ __forceinline__ uint16_t rne_bf16(float f) {
  uint32_t u = __builtin_bit_cast(uint32_t, f);
  u += 0x7fffu + ((u >> 16) & 1u);
  return (uint16_t)(u >> 16);
}

// ---- pre-kernel: W2 [K][O] f32 -> W2T [O][K] bf16; block(0,0) also does b2sum ----
__global__ void prep_w2t(const float* __restrict__ W2, uint16_t* __restrict__ W2T,
                         const float* __restrict__ b2, float* __restrict__ b2sum) {
  __shared__ float tile[64][65];
  const int k0 = blockIdx.x * 64;
  const int o0 = blockIdx.y * 64;
  const int tx = threadIdx.x;  // 0..63
  const int ty = threadIdx.y;  // 0..7
#pragma unroll
  for (int j = 0; j < 8; ++j)
    tile[ty + 8 * j][tx] = W2[(size_t)(k0 + ty + 8 * j) * ODIM + o0 + tx];
  __syncthreads();
#pragma unroll
  for (int j = 0; j < 8; ++j)
    W2T[(size_t)(o0 + ty + 8 * j) * KDIM + k0 + tx] = rne_bf16(tile[tx][ty + 8 * j]);
  if (blockIdx.x == 0 && blockIdx.y == 0) {
    const int o = ty * 64 + tx;  // 0..511
    float s = 0.f;
#pragma unroll
    for (int f = 0; f < FDIM; ++f) s += b2[(size_t)f * ODIM + o];
    b2sum[o] = s;
  }
}

// ---- split-K combine: out = (acc_ko0(out) + acc_ko1(p1) + b2sum) / 8 ----
__global__ void combine_out(const float* __restrict__ p1, const float* __restrict__ b2sum,
                            float* __restrict__ out) {
  const size_t i = ((size_t)blockIdx.x * 256 + threadIdx.x) * 4;
  f32x4 a = *(const f32x4*)(out + i);
  f32x4 b = *(const f32x4*)(p1 + i);
  f32x4 s = *(const f32x4*)(b2sum + (i & 511));
  *(f32x4*)(out + i) = (a + b + s) * 0.125f;
}

// ---- main fused kernel: BM=BN=256, 8 waves of 128x64 wave-tiles, BK=64,
// 128 KB double-buffered LDS (statically-named), split-K=2.
// De-spilled vs r2: NO persistent RegSets; x/W1/b1 loaded inline at stage
// start, ISSUED BEFORE the glds -> FIFO vmcnt means elu's wait is vmcnt(4),
// leaving the 4 B-prefetch glds in flight across elu+MFMA (~full phase).
// Register budget @ launch_bounds(512,2): 256 unified. acc=128 AGPR;
// transient stage regs (~36) die before frag loads (~48) -> peak ~100 VGPR.
template <int KSPLIT>
__global__ __launch_bounds__(512, 2) void mlp_gemm(
    const float* __restrict__ x, const float* __restrict__ W1,
    const float* __restrict__ b1, const uint16_t* __restrict__ W2T,
    const float* __restrict__ b2sum, float* __restrict__ out,
    float* __restrict__ part1) {
  constexpr int NST = (KDIM / BK) / KSPLIT;  // 64 (split) / 128 (fallback)
  __shared__ __align__(16) uint16_t As0[BM * BK];  // 32 KB each
  __shared__ __align__(16) uint16_t As1[BM * BK];
  __shared__ __align__(16) uint16_t Bs0[BN * BK];
  __shared__ __align__(16) uint16_t Bs1[BN * BK];

  const int tid = threadIdx.x;
  const int bid = blockIdx.x;

  int o0, ko, m_idx;
  if constexpr (KSPLIT == 2) {
    // bid&7 = XCD. Fix (o-half, ko) per XCD -> each XCD L2 holds its W2T
    // slice. Bijective over (m 64, o 2, ko 2); grid 256 = 1 block/CU.
    const int g = bid & 7;
    o0 = (g >> 2) * BN;
    ko = g & 1;
    m_idx = (bid >> 3) * 2 + ((g >> 1) & 1);
  } else {
    o0 = (bid & 1) * BN;
    ko = 0;
    m_idx = bid >> 1;
  }
  const int m0 = m_idx * BM;
  const int kbase = ko * NST;

  const int wid = tid >> 6;   // 0..7
  const int lane = tid & 63;
  const int wm = wid >> 2;    // 0..1  wave m-slice (128 rows)
  const int wni = wid & 3;    // 0..3  wave n-slice (64 cols)
  const int q = lane >> 4;
  const int r = lane & 15;

  // A-staging: thread -> rows {ar+64i, i<4}, col-group ac (8 bf16 each)
  const int ar = tid >> 3;  // 0..63
  const int ac = tid & 7;   // 0..7
  const int awc = (ac ^ (ar & 7)) * 8;  // (ar+64i)&7 == ar&7
  // B-staging (glds: LDS dst = wave-uniform base + lane*16; swizzle the
  // GLOBAL col-group so fragment reads stay conflict-free)
  const int brow = lane >> 3;
  const int bcg = (lane & 7) ^ brow;

  f32x4 acc[8][4];
#pragma unroll
  for (int i = 0; i < 8; ++i)
#pragma unroll
    for (int j = 0; j < 4; ++j) acc[i][j] = {0.f, 0.f, 0.f, 0.f};

  // stage step kk into (Ab, Bb): operand loads, then B glds, then elu->A.
  auto stage = [&](uint16_t* Ab, uint16_t* Bb, int kk) {
    const int ks = kbase + kk;
    const int fidx = ks >> 1;
    const int ho = ((ks & 1) << 6) + ac * 8;
    // -- operand loads FIRST (elu's vmcnt wait then leaves glds in flight) --
    const float* wp = W1 + (size_t)fidx * HDIM + ho;
    const float* bp = b1 + (size_t)fidx * HDIM + ho;
    const f32x4 w1lo = *(const f32x4*)wp;
    const f32x4 w1hi = *(const f32x4*)(wp + 4);
    const f32x4 b1lo = *(const f32x4*)bp;
    const f32x4 b1hi = *(const f32x4*)(bp + 4);
    float xv[4];
#pragma unroll
    for (int i = 0; i < 4; ++i)
      xv[i] = x[(size_t)(m0 + i * 64 + ar) * FDIM + fidx];
    // -- B prefetch: 4 async 1KB chunks per wave --
#pragma unroll
    for (int j = 0; j < 4; ++j) {
      const int chunk = wid * 4 + j;
      const uint16_t* gp =
          W2T + (size_t)(o0 + chunk * 8 + brow) * KDIM + ks * BK + bcg * 8;
      uint16_t* lp = Bb + chunk * 512;
      __builtin_amdgcn_global_load_lds(
          (const __attribute__((address_space(1))) uint32_t*)gp,
          (__attribute__((address_space(3))) uint32_t*)lp, 16, 0, 0);
    }
    // -- elu(x*w1+b1) -> bf16 pack -> ds_write (4 rows per thread) --
    float w[8], b[8];
#pragma unroll
    for (int p = 0; p < 4; ++p) {
      w[p * 2] = w1lo[p];     // interleave not needed; index pairs below
      b[p * 2] = b1lo[p];
      w[p * 2 + 1] = w1hi[p];
      b[p * 2 + 1] = b1hi[p];
    }
    // note: w[2p]=w1lo[p] pairs with w[2p+1]=w1hi[p]; the perm pack below
    // writes (lo,hi) bf16 pairs; LDS col order is {lo0,hi0,lo1,hi1,...} --
    // consistent between A-write and B layout because both use the same
    // h-index mapping (ho..ho+7 contiguous = w1lo[0..3],w1hi[0..3] -> we must
    // pack in memory order: elem e of the 8 = wp[e]. wp[0..3]=w1lo, wp[4..7]=w1hi.
#pragma unroll
    for (int i = 0; i < 4; ++i) {
      u32x4 ov;
#pragma unroll
      for (int p = 0; p < 4; ++p) {
        // memory-order elements 2p, 2p+1 within the 8: e = 2p from
        // (p<2 ? w1lo : w1hi)[(2p)&3] ... simpler: rebuild in order:
        float we0 = (p < 2) ? w1lo[2 * p] : w1hi[2 * p - 4];
        float we1 = (p < 2) ? w1lo[2 * p + 1] : w1hi[2 * p - 3];
        float be0 = (p < 2) ? b1lo[2 * p] : b1hi[2 * p - 4];
        float be1 = (p < 2) ? b1lo[2 * p + 1] : b1hi[2 * p - 3];
        float plo = fmaf(xv[i], we0, be0);
        float phi = fmaf(xv[i], we1, be1);
        float elo = fmaxf(plo, __expf(fminf(plo, 0.f)) - 1.f);
        float ehi = fmaxf(phi, __expf(fminf(phi, 0.f)) - 1.f);
        ov[p] = __builtin_amdgcn_perm(__builtin_bit_cast(uint32_t, ehi),
                                      __builtin_bit_cast(uint32_t, elo),
                                      0x07060302u);
      }
      *(u32x4*)(Ab + (i * 64 + ar) * BK + awc) = ov;
    }
  };

  auto compute = [&](const uint16_t* Ab, const uint16_t* Bb) {
#pragma unroll
    for (int kc = 0; kc < 2; ++kc) {
      const int cg = kc * 4 + q;
      bf16x8 af[8], bfr[4];
#pragma unroll
      for (int mt = 0; mt < 8; ++mt) {
        const int row = wm * 128 + mt * 16 + r;
        af[mt] = *(const bf16x8*)&Ab[row * BK + ((cg ^ (row & 7)) * 8)];
      }
#pragma unroll
      for (int nt = 0; nt < 4; ++nt) {
        const int row = wni * 64 + nt * 16 + r;
        bfr[nt] = *(const bf16x8*)&Bb[row * BK + ((cg ^ (row & 7)) * 8)];
      }
#pragma unroll
      for (int mt = 0; mt < 8; ++mt)
#pragma unroll
        for (int nt = 0; nt < 4; ++nt)
          acc[mt][nt] = __builtin_amdgcn_mfma_f32_16x16x32_bf16(
              af[mt], bfr[nt], acc[mt][nt], 0, 0, 0);
    }
  };

  // prologue
  stage(As0, Bs0, 0);
  __syncthreads();

#pragma unroll 1
  for (int kk = 0; kk < NST - 2; kk += 2) {
    stage(As1, Bs1, kk + 1);
    compute(As0, Bs0);
    __syncthreads();
    stage(As0, Bs0, kk + 2);
    compute(As1, Bs1);
    __syncthreads();
  }
  // tail
  stage(As1, Bs1, NST - 1);
  compute(As0, Bs0);
  __syncthreads();
  compute(As1, Bs1);

  // ---- epilogue ----
  if constexpr (KSPLIT == 2) {
    float* P = ko ? part1 : out;
#pragma unroll
    for (int mt = 0; mt < 8; ++mt)
#pragma unroll
      for (int nt = 0; nt < 4; ++nt)
#pragma unroll
        for (int v = 0; v < 4; ++v) {
          const int row = m0 + wm * 128 + mt * 16 + q * 4 + v;
          const int col = o0 + wni * 64 + nt * 16 + r;
          P[(size_t)row * ODIM + col] = acc[mt][nt][v];
        }
  } else {
    float bsv[4];
#pragma unroll
    for (int nt = 0; nt < 4; ++nt) bsv[nt] = b2sum[o0 + wni * 64 + nt * 16 + r];
#pragma unroll
    for (int mt = 0; mt < 8; ++mt)
#pragma unroll
      for (int nt = 0; nt < 4; ++nt)
#pragma unroll
        for (int v = 0; v < 4; ++v) {
          const int row = m0 + wm * 128 + mt * 16 + q * 4 + v;
          const int col = o0 + wni * 64 + nt * 16 + r;
          out[(size_t)row * ODIM + col] = (acc[mt][nt][v] + bsv[nt]) * 0.125f;
        }
  }
}

extern "C" void kernel_launch(void* const* d_in, const int* in_sizes, int n_in,
                              void* d_out, int out_size, void* d_ws, size_t ws_size,
                              hipStream_t stream) {
  const float* x  = (const float*)d_in[0];
  const float* W1 = (const float*)d_in[1];
  const float* b1 = (const float*)d_in[2];
  const float* W2 = (const float*)d_in[3];
  const float* b2 = (const float*)d_in[4];
  float* out = (float*)d_out;

  char* ws = (char*)d_ws;
  const size_t W2T_OFF = 65536;
  const size_t P1_OFF = W2T_OFF + (size_t)ODIM * KDIM * 2;   // +8 MB
  const size_t NEED = P1_OFF + (size_t)NROWS * ODIM * 4;     // +32 MB
  float*    b2sum = (float*)ws;
  uint16_t* W2T   = (uint16_t*)(ws + W2T_OFF);
  float*    part1 = (float*)(ws + P1_OFF);

  prep_w2t<<<dim3(KDIM / 64, ODIM / 64), dim3(64, 8), 0, stream>>>(W2, W2T, b2, b2sum);

  if (ws_size >= NEED) {
    mlp_gemm<2><<<256, 512, 0, stream>>>(x, W1, b1, W2T, b2sum, out, part1);
    combine_out<<<(NROWS * ODIM) / 1024, 256, 0, stream>>>(part1, b2sum, out);
  } else {
    mlp_gemm<1><<<128, 512, 0, stream>>>(x, W1, b1, W2T, b2sum, out, nullptr);
  }
}

// Round 4
// 308.268 us; speedup vs baseline: 1.0288x; 1.0288x over previous
//
#include <hip/hip_runtime.h>
#include <cstdint>

#define NROWS 16384
#define FDIM 64
#define HDIM 128
#define ODIM 512
#define KDIM 8192   // FDIM * HDIM

#define BM 256
#define BN 256
#define BK 64

typedef short bf16x8 __attribute__((ext_vector_type(8)));
typedef float f32x4 __attribute__((ext_vector_type(4)));
typedef uint32_t u32x4 __attribute__((ext_vector_type(4)));

__device__ __forceinline__ uint16_t rne_bf16(float f) {
  uint32_t u = __builtin_bit_cast(uint32_t, f);
  u += 0x7fffu + ((u >> 16) & 1u);
  return (uint16_t)(u >> 16);
}

// ---- pre-kernel: W2 [K][O] f32 -> W2T [O][K] bf16; block(0,0) also does b2sum ----
__global__ void prep_w2t(const float* __restrict__ W2, uint16_t* __restrict__ W2T,
                         const float* __restrict__ b2, float* __restrict__ b2sum) {
  __shared__ float tile[64][65];
  const int k0 = blockIdx.x * 64;
  const int o0 = blockIdx.y * 64;
  const int tx = threadIdx.x;  // 0..63
  const int ty = threadIdx.y;  // 0..7
#pragma unroll
  for (int j = 0; j < 8; ++j)
    tile[ty + 8 * j][tx] = W2[(size_t)(k0 + ty + 8 * j) * ODIM + o0 + tx];
  __syncthreads();
#pragma unroll
  for (int j = 0; j < 8; ++j)
    W2T[(size_t)(o0 + ty + 8 * j) * KDIM + k0 + tx] = rne_bf16(tile[tx][ty + 8 * j]);
  if (blockIdx.x == 0 && blockIdx.y == 0) {
    const int o = ty * 64 + tx;  // 0..511
    float s = 0.f;
#pragma unroll
    for (int f = 0; f < FDIM; ++f) s += b2[(size_t)f * ODIM + o];
    b2sum[o] = s;
  }
}

// ---- split-K combine: out = (acc_ko0(out) + acc_ko1(p1) + b2sum) / 8 ----
__global__ void combine_out(const float* __restrict__ p1, const float* __restrict__ b2sum,
                            float* __restrict__ out) {
  const size_t i = ((size_t)blockIdx.x * 256 + threadIdx.x) * 4;
  f32x4 a = *(const f32x4*)(out + i);
  f32x4 b = *(const f32x4*)(p1 + i);
  f32x4 s = *(const f32x4*)(b2sum + (i & 511));
  *(f32x4*)(out + i) = (a + b + s) * 0.125f;
}

// ---- main fused kernel: BM=BN=256, 8 waves of 128x64 wave-tiles, BK=64,
// 128 KB double-buffered LDS (statically-named), split-K=2.
//
// REGISTER BUDGET (the r2/r3 spill root-cause): LDS=128KB forces 1 block/CU,
// so real occupancy is 8 waves/CU = 2/SIMD regardless of registers. But
// __launch_bounds__(512,2) CAPPED the unified file at 512/2 = 256 regs/wave
// (acc alone = 128) -> ~170MB of scratch spill per dispatch. (512,1) lifts
// the cap to the hw max 512 at zero occupancy cost.
template <int KSPLIT>
__global__ __launch_bounds__(512, 1) void mlp_gemm(
    const float* __restrict__ x, const float* __restrict__ W1,
    const float* __restrict__ b1, const uint16_t* __restrict__ W2T,
    const float* __restrict__ b2sum, float* __restrict__ out,
    float* __restrict__ part1) {
  constexpr int NST = (KDIM / BK) / KSPLIT;  // 64 (split) / 128 (fallback)
  __shared__ __align__(16) uint16_t As0[BM * BK];  // 32 KB each
  __shared__ __align__(16) uint16_t As1[BM * BK];
  __shared__ __align__(16) uint16_t Bs0[BN * BK];
  __shared__ __align__(16) uint16_t Bs1[BN * BK];

  const int tid = threadIdx.x;
  const int bid = blockIdx.x;

  int o0, ko, m_idx;
  if constexpr (KSPLIT == 2) {
    // bid&7 = XCD. Fix (o-half, ko) per XCD -> each XCD L2 holds its W2T
    // slice. Bijective over (m 64, o 2, ko 2); grid 256 = 1 block/CU.
    const int g = bid & 7;
    o0 = (g >> 2) * BN;
    ko = g & 1;
    m_idx = (bid >> 3) * 2 + ((g >> 1) & 1);
  } else {
    o0 = (bid & 1) * BN;
    ko = 0;
    m_idx = bid >> 1;
  }
  const int m0 = m_idx * BM;
  const int kbase = ko * NST;

  const int wid = tid >> 6;   // 0..7
  const int lane = tid & 63;
  const int wm = wid >> 2;    // 0..1  wave m-slice (128 rows)
  const int wni = wid & 3;    // 0..3  wave n-slice (64 cols)
  const int q = lane >> 4;
  const int r = lane & 15;

  // A-staging: thread -> rows {ar+64i, i<4}, col-group ac (8 bf16 each)
  const int ar = tid >> 3;  // 0..63
  const int ac = tid & 7;   // 0..7
  const int awc = (ac ^ (ar & 7)) * 8;  // (ar+64i)&7 == ar&7
  // B-staging (glds: LDS dst = wave-uniform base + lane*16; swizzle the
  // GLOBAL col-group so fragment reads stay conflict-free)
  const int brow = lane >> 3;
  const int bcg = (lane & 7) ^ brow;

  f32x4 acc[8][4];
#pragma unroll
  for (int i = 0; i < 8; ++i)
#pragma unroll
    for (int j = 0; j < 4; ++j) acc[i][j] = {0.f, 0.f, 0.f, 0.f};

  // stage step kk into (Ab, Bb): operand loads, then B glds, then elu->A.
  auto stage = [&](uint16_t* Ab, uint16_t* Bb, int kk) {
    const int ks = kbase + kk;
    const int fidx = ks >> 1;
    const int ho = ((ks & 1) << 6) + ac * 8;
    // -- operand loads FIRST: FIFO vmcnt means elu's operand wait leaves the
    // glds (issued after) still in flight across elu+MFMA --
    const float* wp = W1 + (size_t)fidx * HDIM + ho;
    const float* bp = b1 + (size_t)fidx * HDIM + ho;
    const f32x4 w1lo = *(const f32x4*)wp;    // memory order: elems 0..3
    const f32x4 w1hi = *(const f32x4*)(wp + 4);  // elems 4..7
    const f32x4 b1lo = *(const f32x4*)bp;
    const f32x4 b1hi = *(const f32x4*)(bp + 4);
    float xv[4];
#pragma unroll
    for (int i = 0; i < 4; ++i)
      xv[i] = x[(size_t)(m0 + i * 64 + ar) * FDIM + fidx];
    // -- B prefetch: 4 async 1KB chunks per wave --
#pragma unroll
    for (int j = 0; j < 4; ++j) {
      const int chunk = wid * 4 + j;
      const uint16_t* gp =
          W2T + (size_t)(o0 + chunk * 8 + brow) * KDIM + ks * BK + bcg * 8;
      uint16_t* lp = Bb + chunk * 512;
      __builtin_amdgcn_global_load_lds(
          (const __attribute__((address_space(1))) uint32_t*)gp,
          (__attribute__((address_space(3))) uint32_t*)lp, 16, 0, 0);
    }
    // -- elu(x*w1+b1) -> bf16 pack -> ds_write (4 rows x 8 elems / thread) --
    // pack pairs (2p, 2p+1) in memory order: elems 0..3 from *lo, 4..7 from *hi
#pragma unroll
    for (int i = 0; i < 4; ++i) {
      u32x4 ov;
#pragma unroll
      for (int p = 0; p < 4; ++p) {
        float we0 = (p < 2) ? w1lo[2 * p] : w1hi[2 * p - 4];
        float we1 = (p < 2) ? w1lo[2 * p + 1] : w1hi[2 * p - 3];
        float be0 = (p < 2) ? b1lo[2 * p] : b1hi[2 * p - 4];
        float be1 = (p < 2) ? b1lo[2 * p + 1] : b1hi[2 * p - 3];
        float plo = fmaf(xv[i], we0, be0);
        float phi = fmaf(xv[i], we1, be1);
        float elo = fmaxf(plo, __expf(fminf(plo, 0.f)) - 1.f);
        float ehi = fmaxf(phi, __expf(fminf(phi, 0.f)) - 1.f);
        ov[p] = __builtin_amdgcn_perm(__builtin_bit_cast(uint32_t, ehi),
                                      __builtin_bit_cast(uint32_t, elo),
                                      0x07060302u);
      }
      *(u32x4*)(Ab + (i * 64 + ar) * BK + awc) = ov;
    }
  };

  auto compute = [&](const uint16_t* Ab, const uint16_t* Bb) {
#pragma unroll
    for (int kc = 0; kc < 2; ++kc) {
      const int cg = kc * 4 + q;
      bf16x8 af[8], bfr[4];
#pragma unroll
      for (int mt = 0; mt < 8; ++mt) {
        const int row = wm * 128 + mt * 16 + r;
        af[mt] = *(const bf16x8*)&Ab[row * BK + ((cg ^ (row & 7)) * 8)];
      }
#pragma unroll
      for (int nt = 0; nt < 4; ++nt) {
        const int row = wni * 64 + nt * 16 + r;
        bfr[nt] = *(const bf16x8*)&Bb[row * BK + ((cg ^ (row & 7)) * 8)];
      }
#pragma unroll
      for (int mt = 0; mt < 8; ++mt)
#pragma unroll
        for (int nt = 0; nt < 4; ++nt)
          acc[mt][nt] = __builtin_amdgcn_mfma_f32_16x16x32_bf16(
              af[mt], bfr[nt], acc[mt][nt], 0, 0, 0);
    }
  };

  // prologue
  stage(As0, Bs0, 0);
  __syncthreads();

#pragma unroll 1
  for (int kk = 0; kk < NST - 2; kk += 2) {
    stage(As1, Bs1, kk + 1);
    compute(As0, Bs0);
    __syncthreads();
    stage(As0, Bs0, kk + 2);
    compute(As1, Bs1);
    __syncthreads();
  }
  // tail
  stage(As1, Bs1, NST - 1);
  compute(As0, Bs0);
  __syncthreads();
  compute(As1, Bs1);

  // ---- epilogue ----
  if constexpr (KSPLIT == 2) {
    float* P = ko ? part1 : out;
#pragma unroll
    for (int mt = 0; mt < 8; ++mt)
#pragma unroll
      for (int nt = 0; nt < 4; ++nt)
#pragma unroll
        for (int v = 0; v < 4; ++v) {
          const int row = m0 + wm * 128 + mt * 16 + q * 4 + v;
          const int col = o0 + wni * 64 + nt * 16 + r;
          P[(size_t)row * ODIM + col] = acc[mt][nt][v];
        }
  } else {
    float bsv[4];
#pragma unroll
    for (int nt = 0; nt < 4; ++nt) bsv[nt] = b2sum[o0 + wni * 64 + nt * 16 + r];
#pragma unroll
    for (int mt = 0; mt < 8; ++mt)
#pragma unroll
      for (int nt = 0; nt < 4; ++nt)
#pragma unroll
        for (int v = 0; v < 4; ++v) {
          const int row = m0 + wm * 128 + mt * 16 + q * 4 + v;
          const int col = o0 + wni * 64 + nt * 16 + r;
          out[(size_t)row * ODIM + col] = (acc[mt][nt][v] + bsv[nt]) * 0.125f;
        }
  }
}

extern "C" void kernel_launch(void* const* d_in, const int* in_sizes, int n_in,
                              void* d_out, int out_size, void* d_ws, size_t ws_size,
                              hipStream_t stream) {
  const float* x  = (const float*)d_in[0];
  const float* W1 = (const float*)d_in[1];
  const float* b1 = (const float*)d_in[2];
  const float* W2 = (const float*)d_in[3];
  const float* b2 = (const float*)d_in[4];
  float* out = (float*)d_out;

  char* ws = (char*)d_ws;
  const size_t W2T_OFF = 65536;
  const size_t P1_OFF = W2T_OFF + (size_t)ODIM * KDIM * 2;   // +8 MB
  const size_t NEED = P1_OFF + (size_t)NROWS * ODIM * 4;     // +32 MB
  float*    b2sum = (float*)ws;
  uint16_t* W2T   = (uint16_t*)(ws + W2T_OFF);
  float*    part1 = (float*)(ws + P1_OFF);

  prep_w2t<<<dim3(KDIM / 64, ODIM / 64), dim3(64, 8), 0, stream>>>(W2, W2T, b2, b2sum);

  if (ws_size >= NEED) {
    mlp_gemm<2><<<256, 512, 0, stream>>>(x, W1, b1, W2T, b2sum, out, part1);
    combine_out<<<(NROWS * ODIM) / 1024, 256, 0, stream>>>(part1, b2sum, out);
  } else {
    mlp_gemm<1><<<128, 512, 0, stream>>>(x, W1, b1, W2T, b2sum, out, nullptr);
  }
}